// Round 5
// baseline (691.669 us; speedup 1.0000x reference)
//
#include <hip/hip_runtime.h>
#include <math.h>

#define NSLOTS 50
#define T 101
#define SEQ 2048
#define PD 12          // prefetch distance in steps (2 loads/step -> 24 in flight, vmcnt(22))
#define RING 16        // LDS ring slots (power of 2, > PD)

// v + dpp_permuted(v), pure VALU
template<int CTRL>
__device__ __forceinline__ float dpp_xadd(float v) {
    int x = __builtin_amdgcn_update_dpp(0, __float_as_int(v), CTRL, 0xF, 0xF, true);
    return v + __int_as_float(x);
}

// full 64-lane sum, result uniform in all lanes, no LDS
__device__ __forceinline__ float bfly_sum64(float v) {
    v = dpp_xadd<0xB1>(v);   // quad_perm [1,0,3,2]
    v = dpp_xadd<0x4E>(v);   // quad_perm [2,3,0,1]
    v = dpp_xadd<0x141>(v);  // row_half_mirror
    v = dpp_xadd<0x140>(v);  // row_mirror
#if __has_builtin(__builtin_amdgcn_permlane16_swap)
    {
        auto r = __builtin_amdgcn_permlane16_swap(
            (unsigned)__float_as_int(v), (unsigned)__float_as_int(v), false, false);
        v = __int_as_float((int)r[0]) + __int_as_float((int)r[1]);
    }
#else
    v += __int_as_float(__builtin_amdgcn_ds_swizzle(__float_as_int(v), 0x401F));
#endif
#if __has_builtin(__builtin_amdgcn_permlane32_swap)
    {
        auto r = __builtin_amdgcn_permlane32_swap(
            (unsigned)__float_as_int(v), (unsigned)__float_as_int(v), false, false);
        v = __int_as_float((int)r[0]) + __int_as_float((int)r[1]);
    }
#else
    v += __shfl_xor(v, 32, 64);
#endif
    return v;
}

// async global -> LDS, 4B per lane: LDS[lbase + lane] = *glane
__device__ __forceinline__ void gl_lds(const float* g, float* lbase, int lane) {
#if __has_builtin(__builtin_amdgcn_global_load_lds)
    __builtin_amdgcn_global_load_lds(
        (const __attribute__((address_space(1))) void*)g,
        (__attribute__((address_space(3))) void*)lbase, 4, 0, 0);
#else
    lbase[lane] = *g;
#endif
}

// analytic transition rule (gold score only)
__device__ __forceinline__ float trans_val(const float* L, int i, int j) {
    int ci = (i == 0) ? 0 : ((i & 1) ? 1 : 2);
    int cj = (j == 0) ? 0 : ((j & 1) ? 1 : 2);
    int si = (i - 1) >> 1;
    int sj = (j - 1) >> 1;
    int t1 = (i != 0 && si != sj) ? ((cj == 0) ? 0 : cj + 2) : cj;
    return L[ci * 5 + t1];
}

__global__ __launch_bounds__(128, 1) void crf_nll_kernel(
    const float* __restrict__ feats,      // [B,S,T]
    const float* __restrict__ cdt,        // [3,5] log-probs
    const float* __restrict__ start_t,    // [T]
    const float* __restrict__ stop_t,     // [T]
    const int*   __restrict__ mask,       // [B,S]
    const int*   __restrict__ tags,       // [B,S]
    float*       __restrict__ out)        // [B]
{
    const int b    = blockIdx.x;
    const int tid  = threadIdx.x;
    const int wave = tid >> 6;
    const int l    = tid & 63;
    const float* fb = feats + (size_t)b * SEQ * T;
    const int*   mb = mask + (size_t)b * SEQ;
    const int*   tb = tags + (size_t)b * SEQ;

    __shared__ float S[RING][128];   // per slot: [0..63]=fB lanes, [64..127]=fI lanes (fO at 114)
    __shared__ float gold_lds;

    float L[15];
    #pragma unroll
    for (int i = 0; i < 15; ++i) L[i] = cdt[i];

    // ---- length (both waves, redundant): mask is a prefix of ones ----
    float mc = 0.f;
    for (int t = l; t < SEQ; t += 64) mc += (float)mb[t];
    const int len = (int)(bfly_sum64(mc) + 0.5f);

    float fwd = 0.f;

    if (wave == 1) {
        // ---------------- gold score (hidden behind the scan wave) ----------------
        float gs = 0.f;
        for (int t = l; t < SEQ; t += 64) {
            if (t < len) {
                int tg = tb[t];
                gs += fb[(size_t)t * T + tg];
                if (t >= 1) gs += trans_val(L, tb[t - 1], tg);
            }
        }
        float gold = bfly_sum64(gs);
        gold += start_t[tb[0]] + stop_t[tb[len - 1]];
        if (l == 0) gold_lds = gold;
    } else {
        // ---------------- forward scan, exponent-ratio domain ----------------
        const float pOO = __expf(L[0]),  pOB = __expf(L[1]),  pOI = __expf(L[2]);
        const float pBO = __expf(L[5]),  pBBs = __expf(L[6]), pBIs = __expf(L[7]),
                    pBBd = __expf(L[8]), pBId = __expf(L[9]);
        const float pIO = __expf(L[10]), pIBs = __expf(L[11]), pIIs = __expf(L[12]),
                    pIBd = __expf(L[13]), pIId = __expf(L[14]);
        const float dBB = pBBs - pBBd, dIB = pIBs - pIBd;
        const float dBI = pBIs - pBId, dII = pIIs - pIId;

        const bool act = (l < NSLOTS);
        const int aB = act ? 2 * l + 1 : 100;
        const int aI = act ? 2 * l + 2 : 100;
        // per-lane element offsets within a feats row for the two staged loads
        const int o1 = act ? (2 * l + 1) : 100;                    // -> S[slot][l]
        const int o2 = act ? (2 * l + 2) : ((l == 50) ? 0 : 100);  // -> S[slot][64+l]; fO lands at 114

        // t=0 init (eO == 1 by construction)
        float f0O = fb[0] + start_t[0];
        float eB = act ? __expf((fb[aB] + start_t[aB]) - f0O) : 0.f;
        float eI = act ? __expf((fb[aI] + start_t[aI]) - f0O) : 0.f;
        float accO = f0O, accL = 0.f;

        asm volatile("s_waitcnt vmcnt(0)" ::: "memory");
        // prologue: issue steps 1..PD into the ring (2 loads/step, in step order)
        for (int u = 1; u <= PD; ++u) {
            const float* rowp = fb + (size_t)u * T;
            int s = u & (RING - 1);
            gl_lds(rowp + o1, &S[s][0], l);
            gl_lds(rowp + o2, &S[s][64], l);
        }
        // carried g-factors for step 1
        asm volatile("s_waitcnt vmcnt(22)" ::: "memory");
        float fOc = S[1][114];
        float gBc = act ? __expf(S[1][l] - fOc) : 0.f;
        float gIc = act ? __expf(S[1][64 + l] - fOc) : 0.f;

        for (int t = 1; t < len; ++t) {
            // issue prefetch for step t+PD (clamped; duplicate clamped rows are identical data)
            int u = t + PD; u = (u < SEQ) ? u : (SEQ - 1);
            const float* rowp = fb + (size_t)u * T;
            int ws = u & (RING - 1);
            gl_lds(rowp + o1, &S[ws][0], l);
            gl_lds(rowp + o2, &S[ws][64], l);
            // step t+1's loads (issued PD-1 iters ago) must be done: 2*PD-2 may remain
            asm volatile("s_waitcnt vmcnt(22)" ::: "memory");

            // stage t+1: LDS -> regs, g-factors (off the dependent chain)
            int ns = (t + 1) & (RING - 1);
            float fOn = S[ns][114];
            float fBn = S[ns][l];
            float fIn = S[ns][64 + l];

            // dependent chain for step t (gBc/gIc ready)
            float SBs = bfly_sum64(eB);
            float SIs = bfly_sum64(eI);
            float gBn = act ? __expf(fBn - fOn) : 0.f;   // overlaps butterfly
            float gIn = act ? __expf(fIn - fOn) : 0.f;
            float uB = pOB + eB * dBB + eI * dIB;        // overlaps butterfly
            float uI = pOI + eB * dBI + eI * dII;
            float zB = uB + SBs * pBBd + SIs * pIBd;
            float zI = uI + SBs * pBId + SIs * pIId;
            float zO = pOO + SBs * pBO + SIs * pIO;
#if __has_builtin(__builtin_amdgcn_rcpf)
            float rz = __builtin_amdgcn_rcpf(zO);
#else
            float rz = 1.0f / zO;
#endif
            eB = (gBc * zB) * rz;
            eI = (gIc * zI) * rz;
            accL += __log2f(zO);   // off-chain
            accO += fOc;           // off-chain

            gBc = gBn; gIc = gIn; fOc = fOn;
        }

        accO += accL * 0.6931471805599453f;
        // forward_score = accO + log( sum_j e_j * exp(stop_j) ), eO == 1
        float wsum = act ? eB * __expf(stop_t[aB]) + eI * __expf(stop_t[aI]) : 0.f;
        float sum2 = bfly_sum64(wsum) + __expf(stop_t[0]);
        fwd = accO + __logf(sum2);
    }

    __syncthreads();
    if (tid == 0) out[b] = fwd - gold_lds;
}

extern "C" void kernel_launch(void* const* d_in, const int* in_sizes, int n_in,
                              void* d_out, int out_size, void* d_ws, size_t ws_size,
                              hipStream_t stream) {
    const float* feats   = (const float*)d_in[0];
    const float* cdt     = (const float*)d_in[1];
    const float* start_t = (const float*)d_in[2];
    const float* stop_t  = (const float*)d_in[3];
    const int*   mask    = (const int*)d_in[4];
    const int*   tags    = (const int*)d_in[5];
    float* out = (float*)d_out;

    crf_nll_kernel<<<256, 128, 0, stream>>>(feats, cdt, start_t, stop_t, mask, tags, out);
}

// Round 7
// 290.064 us; speedup vs baseline: 2.3845x; 2.3845x over previous
//
#include <hip/hip_runtime.h>
#include <math.h>

#define NSLOTS 50
#define T 101
#define SEQ 2048
#define CHUNK 16

// v + dpp_permuted(v), pure VALU
template<int CTRL>
__device__ __forceinline__ float dpp_xadd(float v) {
    int x = __builtin_amdgcn_update_dpp(0, __float_as_int(v), CTRL, 0xF, 0xF, true);
    return v + __int_as_float(x);
}

// full 64-lane sum, result uniform in all lanes, no LDS
__device__ __forceinline__ float bfly_sum64(float v) {
    v = dpp_xadd<0xB1>(v);   // quad_perm [1,0,3,2]
    v = dpp_xadd<0x4E>(v);   // quad_perm [2,3,0,1]
    v = dpp_xadd<0x141>(v);  // row_half_mirror
    v = dpp_xadd<0x140>(v);  // row_mirror
#if __has_builtin(__builtin_amdgcn_permlane16_swap)
    { auto r = __builtin_amdgcn_permlane16_swap(
          (unsigned)__float_as_int(v), (unsigned)__float_as_int(v), false, false);
      v = __int_as_float((int)r[0]) + __int_as_float((int)r[1]); }
#else
    v += __int_as_float(__builtin_amdgcn_ds_swizzle(__float_as_int(v), 0x401F));
#endif
#if __has_builtin(__builtin_amdgcn_permlane32_swap)
    { auto r = __builtin_amdgcn_permlane32_swap(
          (unsigned)__float_as_int(v), (unsigned)__float_as_int(v), false, false);
      v = __int_as_float((int)r[0]) + __int_as_float((int)r[1]); }
#else
    v += __shfl_xor(v, 32, 64);
#endif
    return v;
}

__device__ __forceinline__ void gl_lds(const float* g, float* lds) {
#if __has_builtin(__builtin_amdgcn_global_load_lds)
    __builtin_amdgcn_global_load_lds((const __attribute__((address_space(1))) void*)g,
        (__attribute__((address_space(3))) void*)lds, 4, 0, 0);
#else
    lds[threadIdx.x & 63] = *g;
#endif
}

__device__ __forceinline__ float frcp(float x) {
#if __has_builtin(__builtin_amdgcn_rcpf)
    return __builtin_amdgcn_rcpf(x);
#else
    return 1.0f / x;
#endif
}
__device__ __forceinline__ float flog2(float x) {
#if __has_builtin(__builtin_amdgcn_log2f)
    return __builtin_amdgcn_log2f(x);
#else
    return log2f(x);
#endif
}

__global__ __launch_bounds__(128, 1) void crf_nll_kernel(
    const float* __restrict__ feats,      // [B,S,T]
    const float* __restrict__ cdt,        // [3,5] log-probs
    const float* __restrict__ start_t,    // [T]
    const float* __restrict__ stop_t,     // [T]
    const int*   __restrict__ mask,       // [B,S]
    const int*   __restrict__ tags,       // [B,S]
    float*       __restrict__ out)        // [B]
{
    const int b = blockIdx.x, tid = threadIdx.x;
    const int wave = tid >> 6, l = tid & 63;
    const float* fb = feats + (size_t)b * SEQ * T;
    const int*   mb = mask + (size_t)b * SEQ;
    const int*   tb = tags + (size_t)b * SEQ;

    __shared__ float S[64 * 128];   // 4-chunk ring: step t -> slot (t-1)&63, 128 floats/row
    __shared__ float res[2];

    // ---- length (both waves; mask is a prefix of ones) ----
    float mc = 0.f;
    for (int t = l; t < SEQ; t += 64) mc += (float)mb[t];
    const int len    = (int)(bfly_sum64(mc) + 0.5f);
    const int nsteps = len - 1;                 // scan steps t = 1..nsteps
    const int nper   = (nsteps + CHUNK - 1) / CHUNK;
    const int nfull  = nsteps / CHUNK;

    const float actm = (l < NSLOTS) ? 1.f : 0.f;
    const int aB = (2*l+1 <= 100) ? 2*l+1 : 100;
    const int aI = (2*l+2 <= 100) ? 2*l+2 : 100;
    const int s1 = (2*l+1 <= 100) ? 2*l+1 : 0;   // producer: -> S[row][l]   (lane50 -> fO)
    const int s2 = (2*l+2 <= 100) ? 2*l+2 : 0;   // producer: -> S[row][64+l]

    float L[15];
    #pragma unroll
    for (int i = 0; i < 15; ++i) L[i] = cdt[i];
    const float pOO=__expf(L[0]),  pOB=__expf(L[1]),  pOI=__expf(L[2]);
    const float pBO=__expf(L[5]),  pBBs=__expf(L[6]), pBIs=__expf(L[7]),
                pBBd=__expf(L[8]), pBId=__expf(L[9]);
    const float pIO=__expf(L[10]), pIBs=__expf(L[11]), pIIs=__expf(L[12]),
                pIBd=__expf(L[13]), pIId=__expf(L[14]);
    const float dBB=pBBs-pBBd, dIB=pIBs-pIBd, dBI=pBIs-pBId, dII=pIIs-pIId;

    // consumer state: ratio domain, eO == 1 exactly; accF/accL2 = absolute scale
    float eB=0.f, eI=0.f, accF=0.f, accL2=0.f;
    float f0B=0,f0I=0,f0O=0,f1B=0,f1I=0,f1O=0;
    float gs = 0.f;   // producer's gold partial

    if (wave == 1) {
        // stage chunks 0,1 (rows for steps t=1..32)
        #pragma unroll
        for (int k = 0; k < 2*CHUNK; ++k) {
            const float* row = fb + (size_t)(1 + k) * T;
            float* dst = &S[(size_t)k * 128];
            gl_lds(row + s1, dst);
            gl_lds(row + s2, dst + 64);
        }
    } else {
        float pO0 = fb[0] + start_t[0];
        eB = actm * __expf(fb[aB] + start_t[aB] - pO0);
        eI = actm * __expf(fb[aI] + start_t[aI] - pO0);
        accF = pO0;
    }
    __syncthreads();   // chunks 0,1 staged (implicit vmcnt(0) drain on producer)

    if (wave == 0) {   // pipeline fill: steps 1,2
        f0B = S[l];       f0I = S[64 + l];       f0O = S[50];
        f1B = S[128 + l]; f1I = S[128 + 64 + l]; f1O = S[128 + 50];
    }

#define STEP_BODY(GUARDED)                                                    \
    {                                                                         \
        const int t  = 1 + p * CHUNK + k;                                     \
        const int w2 = ((t + 1) & 63) << 7;   /* prefetch row of step t+2 */  \
        float nB = S[w2 + l], nI = S[w2 + 64 + l], nO = S[w2 + 50];           \
        if (!(GUARDED) || t <= nsteps) {                                      \
            float gB = actm * __expf(f0B - f0O);   /* off-chain */            \
            float gI = actm * __expf(f0I - f0O);                              \
            float SBs = bfly_sum64(eB);                                       \
            float SIs = bfly_sum64(eI);                                       \
            float uB = __builtin_fmaf(eB,dBB,__builtin_fmaf(eI,dIB,pOB));     \
            float uI = __builtin_fmaf(eB,dBI,__builtin_fmaf(eI,dII,pOI));     \
            float zB = __builtin_fmaf(SIs,pIBd,__builtin_fmaf(SBs,pBBd,uB));  \
            float zI = __builtin_fmaf(SIs,pIId,__builtin_fmaf(SBs,pBId,uI));  \
            float zO = __builtin_fmaf(SIs,pIO, __builtin_fmaf(SBs,pBO,pOO));  \
            float rz = frcp(zO);                                              \
            eB = (gB * zB) * rz;                                              \
            eI = (gI * zI) * rz;                                              \
            accL2 += flog2(zO);   /* off-chain */                             \
            accF  += f0O;         /* off-chain */                             \
        }                                                                     \
        f0B=f1B; f0I=f1I; f0O=f1O; f1B=nB; f1I=nI; f1O=nO;                    \
    }

    for (int p = 0; p < nper; ++p) {
        if (wave == 0) {
            if (p < nfull) {
                #pragma unroll
                for (int k = 0; k < CHUNK; ++k) STEP_BODY(false)
            } else {
                #pragma unroll
                for (int k = 0; k < CHUNK; ++k) STEP_BODY(true)
            }
        } else {
            const int ci = p + 2;                  // stage chunk p+2
            #pragma unroll
            for (int k = 0; k < CHUNK; ++k) {
                int t = 1 + ci * CHUNK + k;
                t = (t < SEQ) ? t : (SEQ - 1);     // clamp; rows beyond len unused
                const float* row = fb + (size_t)t * T;
                float* dst = &S[(size_t)((ci * CHUNK + k) & 63) * 128];
                gl_lds(row + s1, dst);
                gl_lds(row + s2, dst + 64);
            }
            if (p < (SEQ / 64)) {                  // gold score, spread over periods
                int t0 = (p << 6) + l;
                if (t0 < len) {
                    int tg = tb[t0];
                    gs += fb[(size_t)t0 * T + tg];
                    if (t0 >= 1) {
                        int i  = tb[t0 - 1];
                        int c1 = (i == 0) ? 0 : ((i & 1) ? 1 : 2);
                        int c2 = (tg == 0) ? 0 : ((tg & 1) ? 1 : 2);
                        int si = (i - 1) >> 1, sj = (tg - 1) >> 1;
                        int t1 = (i != 0 && si != sj) ? ((c2 == 0) ? 0 : c2 + 2) : c2;
                        gs += cdt[c1 * 5 + t1];
                    }
                }
            }
        }
        __syncthreads();
    }
#undef STEP_BODY

    if (wave == 0) {
        // forward = accF + ln2*accL2 + ln( sum_j e_j * exp(stop_j) ), eO == 1
        float wsum = actm * (eB * __expf(stop_t[aB]) + eI * __expf(stop_t[aI]));
        float tot  = bfly_sum64(wsum) + __expf(stop_t[0]);
        float fwd  = accF + 0.69314718055994530942f * accL2 + __logf(tot);
        if (l == 0) res[0] = fwd;
    } else {
        float gold = bfly_sum64(gs);
        if (l == 0) res[1] = gold + start_t[tb[0]] + stop_t[tb[len - 1]];
    }
    __syncthreads();
    if (tid == 0) out[b] = res[0] - res[1];
}

extern "C" void kernel_launch(void* const* d_in, const int* in_sizes, int n_in,
                              void* d_out, int out_size, void* d_ws, size_t ws_size,
                              hipStream_t stream) {
    const float* feats   = (const float*)d_in[0];
    const float* cdt     = (const float*)d_in[1];
    const float* start_t = (const float*)d_in[2];
    const float* stop_t  = (const float*)d_in[3];
    const int*   mask    = (const int*)d_in[4];
    const int*   tags    = (const int*)d_in[5];
    float* out = (float*)d_out;

    crf_nll_kernel<<<256, 128, 0, stream>>>(feats, cdt, start_t, stop_t, mask, tags, out);
}

// Round 8
// 266.858 us; speedup vs baseline: 2.5919x; 1.0870x over previous
//
#include <hip/hip_runtime.h>
#include <math.h>

#define NSLOTS 50
#define T 101
#define SEQ 2048
#define CHUNK 16

// v + dpp_permuted(v), pure VALU, all-lanes-valid xor stages
template<int CTRL>
__device__ __forceinline__ float dpp_xadd(float v) {
    int x = __builtin_amdgcn_update_dpp(0, __float_as_int(v), CTRL, 0xF, 0xF, true);
    return v + __int_as_float(x);
}

// Full 64-lane sum -> wave-uniform scalar. Canonical GCN DPP reduction:
// 4 xor stages give each 16-row its sum; row_bcast15/31 accumulate rows;
// lane 63 holds the total; readlane broadcasts it via SGPR.
// No LDS, no permlane builtins -- guaranteed on all CDNA.
__device__ __forceinline__ float wsum64(float v) {
    v = dpp_xadd<0xB1>(v);    // quad_perm [1,0,3,2]  (xor 1)
    v = dpp_xadd<0x4E>(v);    // quad_perm [2,3,0,1]  (xor 2)
    v = dpp_xadd<0x141>(v);   // row_half_mirror      (xor 4)
    v = dpp_xadd<0x140>(v);   // row_mirror           (xor 8)
    v = dpp_xadd<0x142>(v);   // row_bcast15: row1+=row0, row3+=row2
    v = dpp_xadd<0x143>(v);   // row_bcast31: rows2,3 += (row0+row1)
    int s = __builtin_amdgcn_readlane(__float_as_int(v), 63);
    return __int_as_float(s);
}

__device__ __forceinline__ void gl_lds(const float* g, float* lds) {
#if __has_builtin(__builtin_amdgcn_global_load_lds)
    __builtin_amdgcn_global_load_lds((const __attribute__((address_space(1))) void*)g,
        (__attribute__((address_space(3))) void*)lds, 4, 0, 0);
#else
    lds[threadIdx.x & 63] = *g;
#endif
}

__device__ __forceinline__ float frcp(float x) {
#if __has_builtin(__builtin_amdgcn_rcpf)
    return __builtin_amdgcn_rcpf(x);
#else
    return 1.0f / x;
#endif
}
__device__ __forceinline__ float flog2(float x) {
#if __has_builtin(__builtin_amdgcn_log2f)
    return __builtin_amdgcn_log2f(x);
#else
    return log2f(x);
#endif
}

__global__ __launch_bounds__(128, 1) void crf_nll_kernel(
    const float* __restrict__ feats,      // [B,S,T]
    const float* __restrict__ cdt,        // [3,5] log-probs
    const float* __restrict__ start_t,    // [T]
    const float* __restrict__ stop_t,     // [T]
    const int*   __restrict__ mask,       // [B,S]
    const int*   __restrict__ tags,       // [B,S]
    float*       __restrict__ out)        // [B]
{
    const int b = blockIdx.x, tid = threadIdx.x;
    const int wave = tid >> 6, l = tid & 63;
    const float* fb = feats + (size_t)b * SEQ * T;
    const int*   mb = mask + (size_t)b * SEQ;
    const int*   tb = tags + (size_t)b * SEQ;

    __shared__ float S[64 * 128];   // 4-chunk ring: step t -> slot (t-1)&63, 128 floats/row
    __shared__ float res[2];

    // ---- length (both waves; mask is a prefix of ones) ----
    float mc = 0.f;
    for (int t = l; t < SEQ; t += 64) mc += (float)mb[t];
    const int len    = (int)(wsum64(mc) + 0.5f);
    const int nsteps = len - 1;                 // scan steps t = 1..nsteps
    const int nper   = (nsteps + CHUNK - 1) / CHUNK;
    const int nfull  = nsteps / CHUNK;

    const float actm = (l < NSLOTS) ? 1.f : 0.f;
    const int aB = (2*l+1 <= 100) ? 2*l+1 : 100;
    const int aI = (2*l+2 <= 100) ? 2*l+2 : 100;
    const int s1 = (2*l+1 <= 100) ? 2*l+1 : 0;   // producer: -> S[row][l]   (lane50 -> fO)
    const int s2 = (2*l+2 <= 100) ? 2*l+2 : 0;   // producer: -> S[row][64+l]

    float L[15];
    #pragma unroll
    for (int i = 0; i < 15; ++i) L[i] = cdt[i];
    const float pOO=__expf(L[0]),  pOB=__expf(L[1]),  pOI=__expf(L[2]);
    const float pBO=__expf(L[5]),  pBBs=__expf(L[6]), pBIs=__expf(L[7]),
                pBBd=__expf(L[8]), pBId=__expf(L[9]);
    const float pIO=__expf(L[10]), pIBs=__expf(L[11]), pIIs=__expf(L[12]),
                pIBd=__expf(L[13]), pIId=__expf(L[14]);
    const float dBB=pBBs-pBBd, dIB=pIBs-pIBd, dBI=pBIs-pBId, dII=pIIs-pIId;

    // consumer state: ratio domain, eO == 1 exactly; accF/accL2 = absolute scale
    float eB=0.f, eI=0.f, accF=0.f, accL2=0.f;
    float f0B=0,f0I=0,f0O=0,f1B=0,f1I=0,f1O=0;
    float gs = 0.f;   // producer's gold partial

    if (wave == 1) {
        // stage chunks 0,1 (rows for steps t=1..32)
        #pragma unroll
        for (int k = 0; k < 2*CHUNK; ++k) {
            const float* row = fb + (size_t)(1 + k) * T;
            float* dst = &S[(size_t)k * 128];
            gl_lds(row + s1, dst);
            gl_lds(row + s2, dst + 64);
        }
    } else {
        float pO0 = fb[0] + start_t[0];
        eB = actm * __expf(fb[aB] + start_t[aB] - pO0);
        eI = actm * __expf(fb[aI] + start_t[aI] - pO0);
        accF = pO0;
    }
    __syncthreads();   // chunks 0,1 staged (implicit vmcnt(0) drain on producer)

    if (wave == 0) {   // pipeline fill: steps 1,2
        f0B = S[l];       f0I = S[64 + l];       f0O = S[50];
        f1B = S[128 + l]; f1I = S[128 + 64 + l]; f1O = S[128 + 50];
    }

#define STEP_BODY(GUARDED)                                                    \
    {                                                                         \
        const int t  = 1 + p * CHUNK + k;                                     \
        const int w2 = ((t + 1) & 63) << 7;   /* prefetch row of step t+2 */  \
        float nB = S[w2 + l], nI = S[w2 + 64 + l], nO = S[w2 + 50];           \
        if (!(GUARDED) || t <= nsteps) {                                      \
            float gB = actm * __expf(f0B - f0O);   /* off-chain */            \
            float gI = actm * __expf(f0I - f0O);                              \
            float SBs = wsum64(eB);                                           \
            float SIs = wsum64(eI);                                           \
            float uB = __builtin_fmaf(eB,dBB,__builtin_fmaf(eI,dIB,pOB));     \
            float uI = __builtin_fmaf(eB,dBI,__builtin_fmaf(eI,dII,pOI));     \
            float zB = __builtin_fmaf(SIs,pIBd,__builtin_fmaf(SBs,pBBd,uB));  \
            float zI = __builtin_fmaf(SIs,pIId,__builtin_fmaf(SBs,pBId,uI));  \
            float zO = __builtin_fmaf(SIs,pIO, __builtin_fmaf(SBs,pBO,pOO));  \
            float rz = frcp(zO);                                              \
            eB = (gB * zB) * rz;                                              \
            eI = (gI * zI) * rz;                                              \
            accL2 += flog2(zO);   /* off-chain */                             \
            accF  += f0O;         /* off-chain */                             \
        }                                                                     \
        f0B=f1B; f0I=f1I; f0O=f1O; f1B=nB; f1I=nI; f1O=nO;                    \
    }

    for (int p = 0; p < nper; ++p) {
        if (wave == 0) {
            if (p < nfull) {
                #pragma unroll
                for (int k = 0; k < CHUNK; ++k) STEP_BODY(false)
            } else {
                #pragma unroll
                for (int k = 0; k < CHUNK; ++k) STEP_BODY(true)
            }
        } else {
            const int ci = p + 2;                  // stage chunk p+2
            #pragma unroll
            for (int k = 0; k < CHUNK; ++k) {
                int t = 1 + ci * CHUNK + k;
                t = (t < SEQ) ? t : (SEQ - 1);     // clamp; rows beyond len unused
                const float* row = fb + (size_t)t * T;
                float* dst = &S[(size_t)((ci * CHUNK + k) & 63) * 128];
                gl_lds(row + s1, dst);
                gl_lds(row + s2, dst + 64);
            }
            if (p < (SEQ / 64)) {                  // gold score, spread over periods
                int t0 = (p << 6) + l;
                if (t0 < len) {
                    int tg = tb[t0];
                    gs += fb[(size_t)t0 * T + tg];
                    if (t0 >= 1) {
                        int i  = tb[t0 - 1];
                        int c1 = (i == 0) ? 0 : ((i & 1) ? 1 : 2);
                        int c2 = (tg == 0) ? 0 : ((tg & 1) ? 1 : 2);
                        int si = (i - 1) >> 1, sj = (tg - 1) >> 1;
                        int t1 = (i != 0 && si != sj) ? ((c2 == 0) ? 0 : c2 + 2) : c2;
                        gs += cdt[c1 * 5 + t1];
                    }
                }
            }
        }
        __syncthreads();
    }
#undef STEP_BODY

    if (wave == 0) {
        // forward = accF + ln2*accL2 + ln( sum_j e_j * exp(stop_j) ), eO == 1
        float wsum = actm * (eB * __expf(stop_t[aB]) + eI * __expf(stop_t[aI]));
        float tot  = wsum64(wsum) + __expf(stop_t[0]);
        float fwd  = accF + 0.69314718055994530942f * accL2 + __logf(tot);
        if (l == 0) res[0] = fwd;
    } else {
        float gold = wsum64(gs);
        if (l == 0) res[1] = gold + start_t[tb[0]] + stop_t[tb[len - 1]];
    }
    __syncthreads();
    if (tid == 0) out[b] = res[0] - res[1];
}

extern "C" void kernel_launch(void* const* d_in, const int* in_sizes, int n_in,
                              void* d_out, int out_size, void* d_ws, size_t ws_size,
                              hipStream_t stream) {
    const float* feats   = (const float*)d_in[0];
    const float* cdt     = (const float*)d_in[1];
    const float* start_t = (const float*)d_in[2];
    const float* stop_t  = (const float*)d_in[3];
    const int*   mask    = (const int*)d_in[4];
    const int*   tags    = (const int*)d_in[5];
    float* out = (float*)d_out;

    crf_nll_kernel<<<256, 128, 0, stream>>>(feats, cdt, start_t, stop_t, mask, tags, out);
}

// Round 9
// 246.687 us; speedup vs baseline: 2.8038x; 1.0818x over previous
//
#include <hip/hip_runtime.h>
#include <math.h>

#define NSLOTS 50
#define T 101
#define SEQ 2048
#define CHUNK 16

// v + dpp_permuted(v), pure VALU
template<int CTRL>
__device__ __forceinline__ float dpp_xadd(float v) {
    int x = __builtin_amdgcn_update_dpp(0, __float_as_int(v), CTRL, 0xF, 0xF, true);
    return v + __int_as_float(x);
}

// Full 64-lane sum -> wave-uniform scalar (validated in round 8, absmax 0.0)
__device__ __forceinline__ float wsum64(float v) {
    v = dpp_xadd<0xB1>(v);    // xor 1
    v = dpp_xadd<0x4E>(v);    // xor 2
    v = dpp_xadd<0x141>(v);   // xor 4 (row_half_mirror)
    v = dpp_xadd<0x140>(v);   // xor 8 (row_mirror)
    v = dpp_xadd<0x142>(v);   // row_bcast15
    v = dpp_xadd<0x143>(v);   // row_bcast31
    int s = __builtin_amdgcn_readlane(__float_as_int(v), 63);
    return __int_as_float(s);
}

__device__ __forceinline__ void gl_lds(const float* g, float* lds) {
#if __has_builtin(__builtin_amdgcn_global_load_lds)
    __builtin_amdgcn_global_load_lds((const __attribute__((address_space(1))) void*)g,
        (__attribute__((address_space(3))) void*)lds, 4, 0, 0);
#else
    lds[threadIdx.x & 63] = *g;
#endif
}

__global__ __launch_bounds__(192, 1) void crf_nll_kernel(
    const float* __restrict__ feats,      // [B,S,T]
    const float* __restrict__ cdt,        // [3,5] log-probs
    const float* __restrict__ start_t,    // [T]
    const float* __restrict__ stop_t,     // [T]
    const int*   __restrict__ mask,       // [B,S]
    const int*   __restrict__ tags,       // [B,S]
    float*       __restrict__ out)        // [B]
{
    const int b = blockIdx.x, tid = threadIdx.x;
    const int wave = tid >> 6, l = tid & 63;
    const float* fb = feats + (size_t)b * SEQ * T;
    const int*   mb = mask + (size_t)b * SEQ;
    const int*   tb = tags + (size_t)b * SEQ;

    __shared__ float S[64 * 128];   // ring: step t -> slot (t-1)&63; row layout:
                                    // [k]=elem 2k+1 (k<50), [50..63]=elem 0, [64+k]=elem 2k+2
    __shared__ float res[2];

    // ---- length (all waves; mask is a prefix of ones) ----
    float mc = 0.f;
    for (int t = l; t < SEQ; t += 64) mc += (float)mb[t];
    const int len    = (int)(wsum64(mc) + 0.5f);
    const int nsteps = len - 1;                 // scan steps t = 1..nsteps
    const int nper   = (nsteps + CHUNK - 1) / CHUNK;
    const int nfull  = nsteps / CHUNK;

    const float actm = (l < NSLOTS) ? 1.f : 0.f;
    const int aB = (2*l+1 <= 100) ? 2*l+1 : 100;
    const int aI = (2*l+2 <= 100) ? 2*l+2 : 100;
    const int s1 = (2*l+1 <= 100) ? 2*l+1 : 0;   // producer: -> S[row][l] (lanes>=50 -> elem 0)
    const int s2 = (2*l+2 <= 100) ? 2*l+2 : 0;   // producer: -> S[row][64+l]

    const float pOO=__expf(cdt[0]),  pOB=__expf(cdt[1]),  pOI=__expf(cdt[2]);
    const float pBO=__expf(cdt[5]),  pBBs=__expf(cdt[6]), pBIs=__expf(cdt[7]),
                pBBd=__expf(cdt[8]), pBId=__expf(cdt[9]);
    const float pIO=__expf(cdt[10]), pIBs=__expf(cdt[11]), pIIs=__expf(cdt[12]),
                pIBd=__expf(cdt[13]), pIId=__expf(cdt[14]);
    const float dBB=pBBs-pBBd, dIB=pIBs-pIBd, dBI=pBIs-pBId, dII=pIIs-pIId;

    // consumer state: homogeneous (xB,xI,xO); accF = sum fO; accE = sum of rescale exps
    float xB=0.f, xI=0.f, xO=1.f, accF=0.f, uB=0.f, uI=0.f, pOOxO=pOO;
    int accE = 0;
    float f0B=0,f0I=0,f0O=0,f1B=0,f1I=0,f1O=0;
    float gs = 0.f;   // gold partial (wave 2)

    if (wave == 1) {
        // stage chunks 0,1 (rows for steps t=1..32)
        #pragma unroll
        for (int k = 0; k < 2*CHUNK; ++k) {
            const float* row = fb + (size_t)(1 + k) * T;
            float* dst = &S[(size_t)k * 128];
            gl_lds(row + s1, dst);
            gl_lds(row + s2, dst + 64);
        }
    } else if (wave == 0) {
        float pO0 = fb[0] + start_t[0];
        xB = actm * __expf(fb[aB] + start_t[aB] - pO0);
        xI = actm * __expf(fb[aI] + start_t[aI] - pO0);
        accF = pO0;
        uB = __builtin_fmaf(xB, dBB, __builtin_fmaf(xI, dIB, pOB));
        uI = __builtin_fmaf(xB, dBI, __builtin_fmaf(xI, dII, pOI));
    } else {
        if (l == 0) {           // t=0 gold term + start transition
            int tg0 = tb[0];
            gs = fb[tg0] + start_t[tg0];
        }
    }
    __syncthreads();   // chunks 0,1 staged

    if (wave == 0) {   // pipeline fill: steps 1,2
        f0B = S[l];       f0I = S[64 + l];       f0O = S[50];
        f1B = S[128 + l]; f1I = S[128 + 64 + l]; f1O = S[128 + 50];
    }

#define STEP_BODY(GUARDED)                                                     \
    {                                                                          \
        const int t  = 1 + p * CHUNK + k;                                      \
        const int w2 = ((t + 1) & 63) << 7;   /* slot of step t+2 */           \
        float nB = S[w2 + l], nI = S[w2 + 64 + l], nO = S[w2 + 50];            \
        if (!(GUARDED) || t <= nsteps) {                                       \
            float gB = actm * __expf(f0B - f0O);   /* off-chain */             \
            float gI = actm * __expf(f0I - f0O);                               \
            int   ke = ((__float_as_int(xO) >> 23) & 0xFF) - 127;              \
            float r  = __int_as_float((127 - ke) << 23);   /* 2^-ke, exact */  \
            accE += ke;                                                        \
            float XB = wsum64(xB);                                             \
            float XI = wsum64(xI);                                             \
            float NOr = __builtin_fmaf(XI,pIO, __builtin_fmaf(XB,pBO, pOOxO));  \
            float NB  = gB * __builtin_fmaf(XI,pIBd, __builtin_fmaf(XB,pBBd, uB)); \
            float NI  = gI * __builtin_fmaf(XI,pIId, __builtin_fmaf(XB,pBId, uI)); \
            xB = NB * r; xI = NI * r; xO = NOr * r;                            \
            pOOxO = pOO * xO;                      /* off-chain for next */    \
            uB = __builtin_fmaf(xB, dBB, __builtin_fmaf(xI, dIB, pOB * xO));   \
            uI = __builtin_fmaf(xB, dBI, __builtin_fmaf(xI, dII, pOI * xO));   \
            accF += f0O;                                                       \
        }                                                                      \
        f0B=f1B; f0I=f1I; f0O=f1O; f1B=nB; f1I=nI; f1O=nO;                     \
    }

    for (int p = 0; p < nper; ++p) {
        if (wave == 0) {
            if (p < nfull) {
                #pragma unroll
                for (int k = 0; k < CHUNK; ++k) STEP_BODY(false)
            } else {
                #pragma unroll
                for (int k = 0; k < CHUNK; ++k) STEP_BODY(true)
            }
        } else if (wave == 1) {
            const int ci = p + 2;                  // stage chunk p+2
            #pragma unroll
            for (int k = 0; k < CHUNK; ++k) {
                int t = 1 + ci * CHUNK + k;
                t = (t < SEQ) ? t : (SEQ - 1);     // clamp; rows beyond len unused
                const float* row = fb + (size_t)t * T;
                float* dst = &S[(size_t)((ci * CHUNK + k) & 63) * 128];
                gl_lds(row + s1, dst);
                gl_lds(row + s2, dst + 64);
            }
        } else {
            // gold wave: process chunk p-1 (its rows stay live until period p+1)
            if (p >= 1 && l < CHUNK) {
                int t = 1 + (p - 1) * CHUNK + l;
                if (t <= nsteps) {
                    int tg = tb[t], tp = tb[t - 1];
                    int c1 = (tp == 0) ? 0 : ((tp & 1) ? 1 : 2);
                    int c2 = (tg == 0) ? 0 : ((tg & 1) ? 1 : 2);
                    int si = (tp - 1) >> 1, sj = (tg - 1) >> 1;
                    int t1 = (tp != 0 && si != sj) ? ((c2 == 0) ? 0 : c2 + 2) : c2;
                    gs += cdt[c1 * 5 + t1];
                    int idx = (tg == 0) ? 50 : ((tg & 1) ? ((tg - 1) >> 1) : (64 + ((tg - 2) >> 1)));
                    gs += S[(((t - 1) & 63) << 7) + idx];
                }
            }
        }
        __syncthreads();
    }
#undef STEP_BODY

    if (wave == 0) {
        // forward = accF + ln2*accE + ln( sum_j x_j * exp(stop_j) )
        float W = actm * (xB * __expf(stop_t[aB]) + xI * __expf(stop_t[aI]));
        float tot = wsum64(W) + xO * __expf(stop_t[0]);
        float fwd = accF + 0.69314718055994530942f * (float)accE + __logf(tot);
        if (l == 0) res[0] = fwd;
    } else if (wave == 2) {
        // final chunk (nper-1): its rows are still intact after the loop
        if (l < CHUNK) {
            int t = 1 + (nper - 1) * CHUNK + l;
            if (t >= 1 && t <= nsteps) {
                int tg = tb[t], tp = tb[t - 1];
                int c1 = (tp == 0) ? 0 : ((tp & 1) ? 1 : 2);
                int c2 = (tg == 0) ? 0 : ((tg & 1) ? 1 : 2);
                int si = (tp - 1) >> 1, sj = (tg - 1) >> 1;
                int t1 = (tp != 0 && si != sj) ? ((c2 == 0) ? 0 : c2 + 2) : c2;
                gs += cdt[c1 * 5 + t1];
                int idx = (tg == 0) ? 50 : ((tg & 1) ? ((tg - 1) >> 1) : (64 + ((tg - 2) >> 1)));
                gs += S[(((t - 1) & 63) << 7) + idx];
            }
        }
        float gold = wsum64(gs);
        if (l == 0) res[1] = gold + stop_t[tb[len - 1]];
    }
    __syncthreads();
    if (tid == 0) out[b] = res[0] - res[1];
}

extern "C" void kernel_launch(void* const* d_in, const int* in_sizes, int n_in,
                              void* d_out, int out_size, void* d_ws, size_t ws_size,
                              hipStream_t stream) {
    const float* feats   = (const float*)d_in[0];
    const float* cdt     = (const float*)d_in[1];
    const float* start_t = (const float*)d_in[2];
    const float* stop_t  = (const float*)d_in[3];
    const int*   mask    = (const int*)d_in[4];
    const int*   tags    = (const int*)d_in[5];
    float* out = (float*)d_out;

    crf_nll_kernel<<<256, 192, 0, stream>>>(feats, cdt, start_t, stop_t, mask, tags, out);
}